// Round 1
// baseline (529.487 us; speedup 1.0000x reference)
//
#include <hip/hip_runtime.h>
#include <hip/hip_bf16.h>
#include <cmath>

#define TSEQ 2048
#define DMODEL 1024
#define NHEAD 16
#define HDIM 64
#define BATCH 4
#define MTOT (BATCH*TSEQ)   // 8192

typedef __attribute__((ext_vector_type(8))) short bf16x8;
typedef __attribute__((ext_vector_type(4))) float f32x4;
typedef unsigned short u16;

__device__ __forceinline__ u16 f2bf(float f) {
    union { float f; unsigned u; } v; v.f = f;
    unsigned r = (v.u + 0x7fffu + ((v.u >> 16) & 1u)) >> 16;
    return (u16)r;
}

// ---------------- converters ----------------
__global__ __launch_bounds__(256) void cvt_x(const float* __restrict__ x,
                                             u16* __restrict__ xb) {
    int i = (blockIdx.x * 256 + threadIdx.x) * 4;
    float4 v = *(const float4*)(x + i);
    ushort4 o;
    o.x = f2bf(v.x); o.y = f2bf(v.y); o.z = f2bf(v.z); o.w = f2bf(v.w);
    *(ushort4*)(xb + i) = o;
}

// WT[n][k] = bf16(W[k][n]); 64x64 tiles
__global__ __launch_bounds__(256) void wtrans(const float* __restrict__ W,
                                              u16* __restrict__ WT) {
    __shared__ float tile[64][65];
    int n0 = blockIdx.x * 64, k0 = blockIdx.y * 64;
    int t = threadIdx.x;
    int r = t >> 4;            // 0..15
    int c4 = (t & 15) * 4;     // 0..60
#pragma unroll
    for (int rr = 0; rr < 4; rr++) {
        int k = rr * 16 + r;
        float4 v = *(const float4*)(W + (size_t)(k0 + k) * DMODEL + n0 + c4);
        tile[k][c4 + 0] = v.x; tile[k][c4 + 1] = v.y;
        tile[k][c4 + 2] = v.z; tile[k][c4 + 3] = v.w;
    }
    __syncthreads();
#pragma unroll
    for (int rr = 0; rr < 4; rr++) {
        int n = rr * 16 + r;
        ushort4 o;
        o.x = f2bf(tile[c4 + 0][n]);
        o.y = f2bf(tile[c4 + 1][n]);
        o.z = f2bf(tile[c4 + 2][n]);
        o.w = f2bf(tile[c4 + 3][n]);
        *(ushort4*)(WT + (size_t)(n0 + n) * DMODEL + k0 + c4) = o;
    }
}

// ---------------- GEMM: C[M,N] = A[M,K] @ B^T[N,K]^T + bias ----------------
// MODE 0: write bf16 to [B*H][T][HDIM]   (Q, K)
// MODE 1: write bf16 to [B*H][HDIM][T]   (V transposed)
// MODE 3: write f32  to [M][N]           (final output)
template<int MODE>
__global__ __launch_bounds__(256) void gemm_bt(const u16* __restrict__ A,
                                               const u16* __restrict__ BT,
                                               const float* __restrict__ bias,
                                               void* __restrict__ Cout,
                                               int K) {
    __shared__ __align__(16) u16 lA[128 * 32];
    __shared__ __align__(16) u16 lB[128 * 32];
    int m0 = blockIdx.y * 128, n0 = blockIdx.x * 128;
    int t = threadIdx.x, l = t & 63, w = t >> 6;
    int wr = w >> 1, wc = w & 1;
    int lg = l >> 4, lr = l & 15;
    f32x4 acc[4][4];
#pragma unroll
    for (int i = 0; i < 4; i++)
#pragma unroll
        for (int j = 0; j < 4; j++) acc[i][j] = (f32x4){0.f, 0.f, 0.f, 0.f};

    for (int k0 = 0; k0 < K; k0 += 32) {
#pragma unroll
        for (int s = 0; s < 2; s++) {
            int cc = t + s * 256;
            int row = cc >> 2, ko = (cc & 3) * 8;
            *(uint4*)(lA + row * 32 + ko) =
                *(const uint4*)(A + (size_t)(m0 + row) * K + k0 + ko);
            *(uint4*)(lB + row * 32 + ko) =
                *(const uint4*)(BT + (size_t)(n0 + row) * K + k0 + ko);
        }
        __syncthreads();
        bf16x8 af[4], bfr[4];
#pragma unroll
        for (int i = 0; i < 4; i++) {
            af[i]  = *(bf16x8*)(lA + (wr * 64 + i * 16 + lr) * 32 + lg * 8);
            bfr[i] = *(bf16x8*)(lB + (wc * 64 + i * 16 + lr) * 32 + lg * 8);
        }
#pragma unroll
        for (int mi = 0; mi < 4; mi++)
#pragma unroll
            for (int ni = 0; ni < 4; ni++)
                acc[mi][ni] = __builtin_amdgcn_mfma_f32_16x16x32_bf16(
                    af[mi], bfr[ni], acc[mi][ni], 0, 0, 0);
        __syncthreads();
    }

#pragma unroll
    for (int mi = 0; mi < 4; mi++)
#pragma unroll
        for (int ni = 0; ni < 4; ni++)
#pragma unroll
            for (int r = 0; r < 4; r++) {
                int mg = m0 + wr * 64 + mi * 16 + lg * 4 + r;
                int ng = n0 + wc * 64 + ni * 16 + lr;
                float v = acc[mi][ni][r] + bias[ng];
                if (MODE == 0) {
                    int b = mg >> 11, tq = mg & 2047, h = ng >> 6, d = ng & 63;
                    ((u16*)Cout)[(((size_t)(b * NHEAD + h)) * TSEQ + tq) * HDIM + d] = f2bf(v);
                } else if (MODE == 1) {
                    int b = mg >> 11, tq = mg & 2047, h = ng >> 6, d = ng & 63;
                    ((u16*)Cout)[(((size_t)(b * NHEAD + h)) * HDIM + d) * TSEQ + tq] = f2bf(v);
                } else {
                    ((float*)Cout)[(size_t)mg * DMODEL + ng] = v;
                }
            }
}

// ---------------- flash attention (causal) ----------------
// Q,K: [B*H][T][64] bf16; VT: [B*H][64][T] bf16; O: [M][D] bf16
__global__ __launch_bounds__(256) void attn(const u16* __restrict__ Qg,
                                            const u16* __restrict__ Kg,
                                            const u16* __restrict__ VTg,
                                            u16* __restrict__ Og) {
    __shared__ __align__(16) u16 sK[64 * 64];
    __shared__ __align__(16) u16 sV[64 * 64];   // [d][kv]
    __shared__ __align__(16) u16 sP[4][16 * 64];
    int bh = blockIdx.y, qb = blockIdx.x;
    int t = threadIdx.x, l = t & 63, w = t >> 6;
    int lg = l >> 4, lr = l & 15;
    int q0 = qb * 64 + w * 16;

    bf16x8 qf[2];
    const u16* qbase = Qg + ((size_t)bh * TSEQ + q0 + lr) * HDIM + lg * 8;
    qf[0] = *(const bf16x8*)(qbase);
    qf[1] = *(const bf16x8*)(qbase + 32);

    float mrow[4], lrow[4];
    f32x4 accO[4];
#pragma unroll
    for (int r = 0; r < 4; r++) { mrow[r] = -INFINITY; lrow[r] = 0.f; }
#pragma unroll
    for (int nt = 0; nt < 4; nt++) accO[nt] = (f32x4){0.f, 0.f, 0.f, 0.f};
    const float scale = 0.125f;

    for (int kv0 = 0; kv0 <= qb * 64; kv0 += 64) {
        __syncthreads();
#pragma unroll
        for (int s = 0; s < 2; s++) {
            int cc = t + s * 256;
            int row = cc >> 3, ko = (cc & 7) * 8;
            *(uint4*)(sK + row * 64 + ko) =
                *(const uint4*)(Kg + ((size_t)bh * TSEQ + kv0 + row) * HDIM + ko);
            *(uint4*)(sV + row * 64 + ko) =
                *(const uint4*)(VTg + ((size_t)bh * HDIM + row) * TSEQ + kv0 + ko);
        }
        __syncthreads();

        f32x4 Sc[4];
#pragma unroll
        for (int st = 0; st < 4; st++) {
            bf16x8 kf0 = *(bf16x8*)(sK + (st * 16 + lr) * 64 + lg * 8);
            bf16x8 kf1 = *(bf16x8*)(sK + (st * 16 + lr) * 64 + 32 + lg * 8);
            f32x4 s = (f32x4){0.f, 0.f, 0.f, 0.f};
            s = __builtin_amdgcn_mfma_f32_16x16x32_bf16(qf[0], kf0, s, 0, 0, 0);
            s = __builtin_amdgcn_mfma_f32_16x16x32_bf16(qf[1], kf1, s, 0, 0, 0);
            Sc[st] = s;
        }

        float pmax[4], psum[4], fac[4];
#pragma unroll
        for (int r = 0; r < 4; r++) pmax[r] = -INFINITY;
        int qg0 = qb * 64 + w * 16 + lg * 4;
#pragma unroll
        for (int st = 0; st < 4; st++) {
            int kvg = kv0 + st * 16 + lr;
#pragma unroll
            for (int r = 0; r < 4; r++) {
                float s = Sc[st][r] * scale;
                s = (kvg > qg0 + r) ? -INFINITY : s;
                Sc[st][r] = s;
                pmax[r] = fmaxf(pmax[r], s);
            }
        }
#pragma unroll
        for (int x = 1; x < 16; x <<= 1)
#pragma unroll
            for (int r = 0; r < 4; r++)
                pmax[r] = fmaxf(pmax[r], __shfl_xor(pmax[r], x, 64));
#pragma unroll
        for (int r = 0; r < 4; r++) {
            float newm = fmaxf(mrow[r], pmax[r]);
            fac[r] = __expf(mrow[r] - newm);
            mrow[r] = newm;
            psum[r] = 0.f;
        }
#pragma unroll
        for (int st = 0; st < 4; st++)
#pragma unroll
            for (int r = 0; r < 4; r++) {
                float p = __expf(Sc[st][r] - mrow[r]);
                psum[r] += p;
                sP[w][(lg * 4 + r) * 64 + st * 16 + lr] = f2bf(p);
            }
#pragma unroll
        for (int x = 1; x < 16; x <<= 1)
#pragma unroll
            for (int r = 0; r < 4; r++)
                psum[r] += __shfl_xor(psum[r], x, 64);
#pragma unroll
        for (int r = 0; r < 4; r++) lrow[r] = lrow[r] * fac[r] + psum[r];
        __syncthreads();

        bf16x8 pf[2];
        pf[0] = *(bf16x8*)(sP[w] + lr * 64 + lg * 8);
        pf[1] = *(bf16x8*)(sP[w] + lr * 64 + 32 + lg * 8);
#pragma unroll
        for (int nt = 0; nt < 4; nt++) {
#pragma unroll
            for (int r = 0; r < 4; r++) accO[nt][r] *= fac[r];
#pragma unroll
            for (int kk = 0; kk < 2; kk++) {
                bf16x8 vf = *(bf16x8*)(sV + (nt * 16 + lr) * 64 + kk * 32 + lg * 8);
                accO[nt] = __builtin_amdgcn_mfma_f32_16x16x32_bf16(
                    pf[kk], vf, accO[nt], 0, 0, 0);
            }
        }
    }

    int b = bh >> 4, h = bh & 15;
#pragma unroll
    for (int nt = 0; nt < 4; nt++)
#pragma unroll
        for (int r = 0; r < 4; r++) {
            float v = accO[nt][r] / lrow[r];
            int tq = q0 + lg * 4 + r;
            Og[((size_t)(b * TSEQ + tq)) * DMODEL + h * HDIM + nt * 16 + lr] = f2bf(v);
        }
}

// ---------------- launch ----------------
extern "C" void kernel_launch(void* const* d_in, const int* in_sizes, int n_in,
                              void* d_out, int out_size, void* d_ws, size_t ws_size,
                              hipStream_t stream) {
    const float* x  = (const float*)d_in[0];
    const float* Wq = (const float*)d_in[1];
    const float* bq = (const float*)d_in[2];
    const float* Wk = (const float*)d_in[3];
    const float* bk = (const float*)d_in[4];
    const float* Wv = (const float*)d_in[5];
    const float* bv = (const float*)d_in[6];
    const float* Wo = (const float*)d_in[7];
    const float* bo = (const float*)d_in[8];
    float* out = (float*)d_out;

    u16* ws  = (u16*)d_ws;
    u16* xb  = ws;                               // 8M elems
    u16* WqT = xb  + (size_t)MTOT * DMODEL;
    u16* WkT = WqT + (size_t)DMODEL * DMODEL;
    u16* WvT = WkT + (size_t)DMODEL * DMODEL;
    u16* WoT = WvT + (size_t)DMODEL * DMODEL;
    u16* Qg  = WoT + (size_t)DMODEL * DMODEL;
    u16* Kg  = Qg  + (size_t)MTOT * DMODEL;
    u16* VTg = Kg  + (size_t)MTOT * DMODEL;
    u16* Og  = VTg + (size_t)MTOT * DMODEL;      // total ~88 MB

    cvt_x<<<(MTOT * DMODEL) / (256 * 4), 256, 0, stream>>>(x, xb);
    dim3 tg(16, 16);
    wtrans<<<tg, 256, 0, stream>>>(Wq, WqT);
    wtrans<<<tg, 256, 0, stream>>>(Wk, WkT);
    wtrans<<<tg, 256, 0, stream>>>(Wv, WvT);
    wtrans<<<tg, 256, 0, stream>>>(Wo, WoT);

    dim3 gg(DMODEL / 128, MTOT / 128);           // (8, 64)
    gemm_bt<0><<<gg, 256, 0, stream>>>(xb, WqT, bq, Qg, DMODEL);
    gemm_bt<0><<<gg, 256, 0, stream>>>(xb, WkT, bk, Kg, DMODEL);
    gemm_bt<1><<<gg, 256, 0, stream>>>(xb, WvT, bv, VTg, DMODEL);

    attn<<<dim3(TSEQ / 64, BATCH * NHEAD), 256, 0, stream>>>(Qg, Kg, VTg, Og);

    gemm_bt<3><<<gg, 256, 0, stream>>>(Og, WoT, bo, out, DMODEL);
}

// Round 2
// 385.735 us; speedup vs baseline: 1.3727x; 1.3727x over previous
//
#include <hip/hip_runtime.h>
#include <hip/hip_bf16.h>
#include <cmath>

#define TSEQ 2048
#define DMODEL 1024
#define NHEAD 16
#define HDIM 64
#define BATCH 4
#define MTOT (BATCH*TSEQ)   // 8192

typedef __attribute__((ext_vector_type(8))) short bf16x8;
typedef __attribute__((ext_vector_type(4))) float f32x4;
typedef unsigned short u16;
typedef unsigned int u32;

__device__ __forceinline__ u16 f2bf(float f) {
    union { float f; unsigned u; } v; v.f = f;
    unsigned r = (v.u + 0x7fffu + ((v.u >> 16) & 1u)) >> 16;
    return (u16)r;
}

// async global->LDS, 16B per lane; LDS dest must be wave-uniform base (+lane*16 by HW)
#define GLOAD16(g, s) __builtin_amdgcn_global_load_lds( \
    (const __attribute__((address_space(1))) void*)(g), \
    (__attribute__((address_space(3))) void*)(s), 16, 0, 0)

// ---------------- converters ----------------
__global__ __launch_bounds__(256) void cvt_x(const float* __restrict__ x,
                                             u16* __restrict__ xb) {
    int i = (blockIdx.x * 256 + threadIdx.x) * 4;
    float4 v = *(const float4*)(x + i);
    ushort4 o;
    o.x = f2bf(v.x); o.y = f2bf(v.y); o.z = f2bf(v.z); o.w = f2bf(v.w);
    *(ushort4*)(xb + i) = o;
}

// WT[n][k] = bf16(W[k][n]); 64x64 tiles
__global__ __launch_bounds__(256) void wtrans(const float* __restrict__ W,
                                              u16* __restrict__ WT) {
    __shared__ float tile[64][65];
    int n0 = blockIdx.x * 64, k0 = blockIdx.y * 64;
    int t = threadIdx.x;
    int r = t >> 4;            // 0..15
    int c4 = (t & 15) * 4;     // 0..60
#pragma unroll
    for (int rr = 0; rr < 4; rr++) {
        int k = rr * 16 + r;
        float4 v = *(const float4*)(W + (size_t)(k0 + k) * DMODEL + n0 + c4);
        tile[k][c4 + 0] = v.x; tile[k][c4 + 1] = v.y;
        tile[k][c4 + 2] = v.z; tile[k][c4 + 3] = v.w;
    }
    __syncthreads();
#pragma unroll
    for (int rr = 0; rr < 4; rr++) {
        int n = rr * 16 + r;
        ushort4 o;
        o.x = f2bf(tile[c4 + 0][n]);
        o.y = f2bf(tile[c4 + 1][n]);
        o.z = f2bf(tile[c4 + 2][n]);
        o.w = f2bf(tile[c4 + 3][n]);
        *(ushort4*)(WT + (size_t)(n0 + n) * DMODEL + k0 + c4) = o;
    }
}

// ---------------- GEMM: C[M,N] = (A[M,K] @ B^T[N,K]^T + bias) * scale ----------------
// MODE 0: write bf16 to [B*H][T][HDIM]   (Q, K)
// MODE 1: write bf16 to [B*H][HDIM][T]   (V transposed)
// MODE 3: write f32  to [M][N]           (final output)
template<int MODE>
__global__ __launch_bounds__(256) void gemm_bt(const u16* __restrict__ A,
                                               const u16* __restrict__ BT,
                                               const float* __restrict__ bias,
                                               void* __restrict__ Cout,
                                               int K, float scale) {
    __shared__ __align__(16) u16 lA[128 * 32];
    __shared__ __align__(16) u16 lB[128 * 32];
    int m0 = blockIdx.y * 128, n0 = blockIdx.x * 128;
    int t = threadIdx.x, l = t & 63, w = t >> 6;
    int wr = w >> 1, wc = w & 1;
    int lg = l >> 4, lr = l & 15;
    f32x4 acc[4][4];
#pragma unroll
    for (int i = 0; i < 4; i++)
#pragma unroll
        for (int j = 0; j < 4; j++) acc[i][j] = (f32x4){0.f, 0.f, 0.f, 0.f};

    for (int k0 = 0; k0 < K; k0 += 32) {
        __syncthreads();
#pragma unroll
        for (int s = 0; s < 2; s++) {
            int cc = t + s * 256;           // chunk id, 16B each
            int row = cc >> 2, ko = (cc & 3) * 8;
            GLOAD16(A  + (size_t)(m0 + row) * K + k0 + ko,
                    lA + (size_t)(s * 256 + w * 64) * 8);
            GLOAD16(BT + (size_t)(n0 + row) * K + k0 + ko,
                    lB + (size_t)(s * 256 + w * 64) * 8);
        }
        asm volatile("s_waitcnt vmcnt(0)" ::: "memory");
        __syncthreads();
        bf16x8 af[4], bfr[4];
#pragma unroll
        for (int i = 0; i < 4; i++) {
            af[i]  = *(bf16x8*)(lA + (wr * 64 + i * 16 + lr) * 32 + lg * 8);
            bfr[i] = *(bf16x8*)(lB + (wc * 64 + i * 16 + lr) * 32 + lg * 8);
        }
        __builtin_amdgcn_s_setprio(1);
#pragma unroll
        for (int mi = 0; mi < 4; mi++)
#pragma unroll
            for (int ni = 0; ni < 4; ni++)
                acc[mi][ni] = __builtin_amdgcn_mfma_f32_16x16x32_bf16(
                    af[mi], bfr[ni], acc[mi][ni], 0, 0, 0);
        __builtin_amdgcn_s_setprio(0);
    }

#pragma unroll
    for (int mi = 0; mi < 4; mi++)
#pragma unroll
        for (int ni = 0; ni < 4; ni++) {
            int ng = n0 + wc * 64 + ni * 16 + lr;
            int mg0 = m0 + wr * 64 + mi * 16 + lg * 4;
            if (MODE == 1) {
                int b = mg0 >> 11, tq0 = mg0 & 2047, h = ng >> 6, d = ng & 63;
                ushort4 o;
                o.x = f2bf((acc[mi][ni][0] + bias[ng]) * scale);
                o.y = f2bf((acc[mi][ni][1] + bias[ng]) * scale);
                o.z = f2bf((acc[mi][ni][2] + bias[ng]) * scale);
                o.w = f2bf((acc[mi][ni][3] + bias[ng]) * scale);
                *(ushort4*)&((u16*)Cout)[(((size_t)(b * NHEAD + h)) * HDIM + d) * TSEQ + tq0] = o;
            } else {
#pragma unroll
                for (int r = 0; r < 4; r++) {
                    int mg = mg0 + r;
                    float v = (acc[mi][ni][r] + bias[ng]) * scale;
                    if (MODE == 0) {
                        int b = mg >> 11, tq = mg & 2047, h = ng >> 6, d = ng & 63;
                        ((u16*)Cout)[(((size_t)(b * NHEAD + h)) * TSEQ + tq) * HDIM + d] = f2bf(v);
                    } else {
                        ((float*)Cout)[(size_t)mg * DMODEL + ng] = v;
                    }
                }
            }
        }
}

// ---------------- flash attention (causal), swapped-QK, swizzled LDS ----------------
// Q,K: [B*H][T][64] bf16 (Q pre-scaled by 0.125); VT: [B*H][64][T] bf16; O: [M][D] bf16
__global__ __launch_bounds__(256) void attn(const u16* __restrict__ Qg,
                                            const u16* __restrict__ Kg,
                                            const u16* __restrict__ VTg,
                                            u16* __restrict__ Og) {
    __shared__ __align__(16) u16 sK[64 * 64];
    __shared__ __align__(16) u16 sV[64 * 64];   // [d][kv]
    __shared__ __align__(16) u16 sP[4][16 * 64];
    int bh = blockIdx.y, qb = blockIdx.x;
    int t = threadIdx.x, l = t & 63, w = t >> 6;
    int lg = l >> 4, lr = l & 15;
    int q0 = qb * 64 + w * 16;
    int qglob = q0 + lr;        // this lane's q row (swapped layout)
    int rsw = lr & 7;

    bf16x8 qf[2];
    const u16* qbase = Qg + ((size_t)bh * TSEQ + qglob) * HDIM + lg * 8;
    qf[0] = *(const bf16x8*)(qbase);
    qf[1] = *(const bf16x8*)(qbase + 32);

    float m = -INFINITY, lsum = 0.f;
    f32x4 accO[4];
#pragma unroll
    for (int nt = 0; nt < 4; nt++) accO[nt] = (f32x4){0.f, 0.f, 0.f, 0.f};

    for (int kv0 = 0; kv0 <= qb * 64; kv0 += 64) {
        __syncthreads();
        // stage K,V; linear LDS dest, inverse-swizzled global source (chunk ^= row&7)
#pragma unroll
        for (int s = 0; s < 2; s++) {
            int cc = t + s * 256;
            int row = cc >> 3;
            int csrc = (cc ^ row) & 7;
            GLOAD16(Kg  + ((size_t)bh * TSEQ + kv0 + row) * HDIM + csrc * 8,
                    sK + (size_t)(s * 256 + w * 64) * 8);
            GLOAD16(VTg + ((size_t)bh * HDIM + row) * TSEQ + kv0 + csrc * 8,
                    sV + (size_t)(s * 256 + w * 64) * 8);
        }
        asm volatile("s_waitcnt vmcnt(0)" ::: "memory");
        __syncthreads();

        // S^T = K.Q^T : lane holds S[q=lr][kv = kv0 + st*16 + lg*4 + r]
        f32x4 Sc[4];
        __builtin_amdgcn_s_setprio(1);
#pragma unroll
        for (int st = 0; st < 4; st++) {
            int row = st * 16 + lr;
            bf16x8 kf0 = *(const bf16x8*)(sK + row * 64 + ((lg ^ rsw) << 3));
            bf16x8 kf1 = *(const bf16x8*)(sK + row * 64 + (((4 | lg) ^ rsw) << 3));
            f32x4 s = (f32x4){0.f, 0.f, 0.f, 0.f};
            s = __builtin_amdgcn_mfma_f32_16x16x32_bf16(kf0, qf[0], s, 0, 0, 0);
            s = __builtin_amdgcn_mfma_f32_16x16x32_bf16(kf1, qf[1], s, 0, 0, 0);
            Sc[st] = s;
        }
        __builtin_amdgcn_s_setprio(0);

        // mask + row max (row is lane-local + 2 shuffles)
        float pmax = -INFINITY;
#pragma unroll
        for (int st = 0; st < 4; st++)
#pragma unroll
            for (int r = 0; r < 4; r++) {
                int kvg = kv0 + st * 16 + lg * 4 + r;
                float v = Sc[st][r];
                v = (kvg > qglob) ? -INFINITY : v;
                Sc[st][r] = v;
                pmax = fmaxf(pmax, v);
            }
        pmax = fmaxf(pmax, __shfl_xor(pmax, 16, 64));
        pmax = fmaxf(pmax, __shfl_xor(pmax, 32, 64));
        float newm = fmaxf(m, pmax);
        float fac = __expf(m - newm);
        m = newm;

        // P = exp(S-m), packed b64 writes into swizzled sP
        float psum = 0.f;
#pragma unroll
        for (int st = 0; st < 4; st++) {
            float p0 = __expf(Sc[st][0] - m);
            float p1 = __expf(Sc[st][1] - m);
            float p2 = __expf(Sc[st][2] - m);
            float p3 = __expf(Sc[st][3] - m);
            psum += (p0 + p1) + (p2 + p3);
            u32 w0 = (u32)f2bf(p0) | ((u32)f2bf(p1) << 16);
            u32 w1 = (u32)f2bf(p2) | ((u32)f2bf(p3) << 16);
            int c16 = (st << 1) | (lg >> 1);
            char* dst = (char*)(sP[w]) + lr * 128 + ((c16 ^ rsw) << 4) + ((lg & 1) << 3);
            *(uint2*)dst = make_uint2(w0, w1);
        }
        psum += __shfl_xor(psum, 16, 64);
        psum += __shfl_xor(psum, 32, 64);
        lsum = lsum * fac + psum;

        // broadcast fac from q=lr lanes to accO rows q=lg*4+r
        float facr0 = __shfl(fac, lg * 4 + 0, 16);
        float facr1 = __shfl(fac, lg * 4 + 1, 16);
        float facr2 = __shfl(fac, lg * 4 + 2, 16);
        float facr3 = __shfl(fac, lg * 4 + 3, 16);

        bf16x8 pf0 = *(const bf16x8*)((char*)(sP[w]) + lr * 128 + ((lg ^ rsw) << 4));
        bf16x8 pf1 = *(const bf16x8*)((char*)(sP[w]) + lr * 128 + (((4 | lg) ^ rsw) << 4));

        __builtin_amdgcn_s_setprio(1);
#pragma unroll
        for (int nt = 0; nt < 4; nt++) {
            f32x4 a = accO[nt];
            a[0] *= facr0; a[1] *= facr1; a[2] *= facr2; a[3] *= facr3;
            int vrow = nt * 16 + lr;
            bf16x8 vf0 = *(const bf16x8*)(sV + vrow * 64 + ((lg ^ rsw) << 3));
            bf16x8 vf1 = *(const bf16x8*)(sV + vrow * 64 + (((4 | lg) ^ rsw) << 3));
            a = __builtin_amdgcn_mfma_f32_16x16x32_bf16(pf0, vf0, a, 0, 0, 0);
            a = __builtin_amdgcn_mfma_f32_16x16x32_bf16(pf1, vf1, a, 0, 0, 0);
            accO[nt] = a;
        }
        __builtin_amdgcn_s_setprio(0);
    }

    float linv = 1.0f / lsum;
    float li0 = __shfl(linv, lg * 4 + 0, 16);
    float li1 = __shfl(linv, lg * 4 + 1, 16);
    float li2 = __shfl(linv, lg * 4 + 2, 16);
    float li3 = __shfl(linv, lg * 4 + 3, 16);
    int b = bh >> 4, h = bh & 15;
#pragma unroll
    for (int nt = 0; nt < 4; nt++) {
        int d = h * HDIM + nt * 16 + lr;
        int tq0 = q0 + lg * 4;
        Og[((size_t)(b * TSEQ + tq0 + 0)) * DMODEL + d] = f2bf(accO[nt][0] * li0);
        Og[((size_t)(b * TSEQ + tq0 + 1)) * DMODEL + d] = f2bf(accO[nt][1] * li1);
        Og[((size_t)(b * TSEQ + tq0 + 2)) * DMODEL + d] = f2bf(accO[nt][2] * li2);
        Og[((size_t)(b * TSEQ + tq0 + 3)) * DMODEL + d] = f2bf(accO[nt][3] * li3);
    }
}

// ---------------- launch ----------------
extern "C" void kernel_launch(void* const* d_in, const int* in_sizes, int n_in,
                              void* d_out, int out_size, void* d_ws, size_t ws_size,
                              hipStream_t stream) {
    const float* x  = (const float*)d_in[0];
    const float* Wq = (const float*)d_in[1];
    const float* bq = (const float*)d_in[2];
    const float* Wk = (const float*)d_in[3];
    const float* bk = (const float*)d_in[4];
    const float* Wv = (const float*)d_in[5];
    const float* bv = (const float*)d_in[6];
    const float* Wo = (const float*)d_in[7];
    const float* bo = (const float*)d_in[8];
    float* out = (float*)d_out;

    u16* ws  = (u16*)d_ws;
    u16* xb  = ws;                               // 8M elems
    u16* WqT = xb  + (size_t)MTOT * DMODEL;
    u16* WkT = WqT + (size_t)DMODEL * DMODEL;
    u16* WvT = WkT + (size_t)DMODEL * DMODEL;
    u16* WoT = WvT + (size_t)DMODEL * DMODEL;
    u16* Qg  = WoT + (size_t)DMODEL * DMODEL;
    u16* Kg  = Qg  + (size_t)MTOT * DMODEL;
    u16* VTg = Kg  + (size_t)MTOT * DMODEL;
    u16* Og  = VTg + (size_t)MTOT * DMODEL;      // total ~88 MB

    cvt_x<<<(MTOT * DMODEL) / (256 * 4), 256, 0, stream>>>(x, xb);
    dim3 tg(16, 16);
    wtrans<<<tg, 256, 0, stream>>>(Wq, WqT);
    wtrans<<<tg, 256, 0, stream>>>(Wk, WkT);
    wtrans<<<tg, 256, 0, stream>>>(Wv, WvT);
    wtrans<<<tg, 256, 0, stream>>>(Wo, WoT);

    dim3 gg(DMODEL / 128, MTOT / 128);           // (8, 64)
    gemm_bt<0><<<gg, 256, 0, stream>>>(xb, WqT, bq, Qg, DMODEL, 0.125f);  // Q pre-scaled
    gemm_bt<0><<<gg, 256, 0, stream>>>(xb, WkT, bk, Kg, DMODEL, 1.0f);
    gemm_bt<1><<<gg, 256, 0, stream>>>(xb, WvT, bv, VTg, DMODEL, 1.0f);

    attn<<<dim3(TSEQ / 64, BATCH * NHEAD), 256, 0, stream>>>(Qg, Kg, VTg, Og);

    gemm_bt<3><<<gg, 256, 0, stream>>>(Og, WoT, bo, out, DMODEL, 1.0f);
}

// Round 4
// 307.298 us; speedup vs baseline: 1.7230x; 1.2552x over previous
//
#include <hip/hip_runtime.h>
#include <hip/hip_bf16.h>
#include <cmath>

#define TSEQ 2048
#define DMODEL 1024
#define NHEAD 16
#define HDIM 64
#define BATCH 4
#define MTOT (BATCH*TSEQ)   // 8192

typedef __attribute__((ext_vector_type(8))) short bf16x8;
typedef __attribute__((ext_vector_type(4))) float f32x4;
typedef __attribute__((ext_vector_type(16))) float f32x16;
typedef unsigned short u16;
typedef unsigned int u32;
typedef __attribute__((ext_vector_type(2))) unsigned int u32x2;

#define QSCALE 0.18033688011112042f   // 0.125 * log2(e)

__device__ __forceinline__ u16 f2bf(float f) {
    union { float f; unsigned u; } v; v.f = f;
    unsigned r = (v.u + 0x7fffu + ((v.u >> 16) & 1u)) >> 16;
    return (u16)r;
}

__device__ __forceinline__ u32 cvtpk(float a, float b) {
    u32 r;
    asm("v_cvt_pk_bf16_f32 %0, %1, %2" : "=v"(r) : "v"(a), "v"(b));
    return r;
}

// async global->LDS, 16B per lane; LDS dest is wave-uniform base (+lane*16 by HW)
#define GLOAD16(g, s) __builtin_amdgcn_global_load_lds( \
    (const __attribute__((address_space(1))) void*)(g), \
    (__attribute__((address_space(3))) void*)(s), 16, 0, 0)

// ---------------- converters ----------------
__global__ __launch_bounds__(256) void cvt_x(const float* __restrict__ x,
                                             u16* __restrict__ xb) {
    int i = (blockIdx.x * 256 + threadIdx.x) * 4;
    float4 v = *(const float4*)(x + i);
    ushort4 o;
    o.x = f2bf(v.x); o.y = f2bf(v.y); o.z = f2bf(v.z); o.w = f2bf(v.w);
    *(ushort4*)(xb + i) = o;
}

// WT[n][k] = bf16(W[k][n]); 64x64 tiles
__global__ __launch_bounds__(256) void wtrans(const float* __restrict__ W,
                                              u16* __restrict__ WT) {
    __shared__ float tile[64][65];
    int n0 = blockIdx.x * 64, k0 = blockIdx.y * 64;
    int t = threadIdx.x;
    int r = t >> 4;
    int c4 = (t & 15) * 4;
#pragma unroll
    for (int rr = 0; rr < 4; rr++) {
        int k = rr * 16 + r;
        float4 v = *(const float4*)(W + (size_t)(k0 + k) * DMODEL + n0 + c4);
        tile[k][c4 + 0] = v.x; tile[k][c4 + 1] = v.y;
        tile[k][c4 + 2] = v.z; tile[k][c4 + 3] = v.w;
    }
    __syncthreads();
#pragma unroll
    for (int rr = 0; rr < 4; rr++) {
        int n = rr * 16 + r;
        ushort4 o;
        o.x = f2bf(tile[c4 + 0][n]);
        o.y = f2bf(tile[c4 + 1][n]);
        o.z = f2bf(tile[c4 + 2][n]);
        o.w = f2bf(tile[c4 + 3][n]);
        *(ushort4*)(WT + (size_t)(n0 + n) * DMODEL + k0 + c4) = o;
    }
}

__global__ __launch_bounds__(256) void pack_bias(const float* __restrict__ bq,
                                                 const float* __restrict__ bk,
                                                 const float* __restrict__ bv,
                                                 float* __restrict__ bp) {
    int i = blockIdx.x * 256 + threadIdx.x;   // 0..3071
    float v = (i < 1024) ? bq[i] * QSCALE : (i < 2048) ? bk[i - 1024] : bv[i - 2048];
    bp[i] = v;
}

// ---------------- GEMM: 128x128 tile, BK=32, double-buffered 2-phase ----------------
// MODE 0: fused QKV (N=3072): seg0->Qg (pre-scaled by QSCALE), seg1->Kg, seg2->VTg
// MODE 3: f32 out [M][N]
template<int MODE>
__global__ __launch_bounds__(256) void gemm_bt(const u16* __restrict__ A,
                                               const u16* __restrict__ BT,
                                               const float* __restrict__ bias,
                                               u16* __restrict__ Qg,
                                               u16* __restrict__ Kg,
                                               u16* __restrict__ VTg,
                                               float* __restrict__ Fout,
                                               int K) {
    __shared__ __align__(16) u16 lA[2 * 4096];
    __shared__ __align__(16) u16 lB[2 * 4096];
    // XCD-chunked swizzle (nwg multiple of 8)
    int nwg = gridDim.x * gridDim.y;
    int bid = blockIdx.y * gridDim.x + blockIdx.x;
    int cpx = nwg >> 3;
    int swz = (bid & 7) * cpx + (bid >> 3);
    int bx = swz % gridDim.x, by = swz / gridDim.x;
    int m0 = by * 128, n0 = bx * 128;
    int t = threadIdx.x, l = t & 63, w = t >> 6;
    int wr = w >> 1, wc = w & 1;
    int lg = l >> 4, lr = l & 15;
    f32x4 acc[4][4];
#pragma unroll
    for (int i = 0; i < 4; i++)
#pragma unroll
        for (int j = 0; j < 4; j++) acc[i][j] = (f32x4){0.f, 0.f, 0.f, 0.f};

    auto STAGE = [&](int kt, int nbuf) {
        int k0 = kt << 5;
#pragma unroll
        for (int s = 0; s < 2; ++s) {
            int cc = t + s * 256;
            int row = cc >> 2, ko = (cc & 3) * 8;
            GLOAD16(A  + (size_t)(m0 + row) * K + k0 + ko,
                    lA + nbuf * 4096 + (s * 256 + w * 64) * 8);
            GLOAD16(BT + (size_t)(n0 + row) * K + k0 + ko,
                    lB + nbuf * 4096 + (s * 256 + w * 64) * 8);
        }
    };

    STAGE(0, 0);
    asm volatile("s_waitcnt vmcnt(0)" ::: "memory");
    __syncthreads();
    int nb = 0;
    int KT = K >> 5;
    for (int kt = 0; kt < KT; ++kt) {
        if (kt + 1 < KT) STAGE(kt + 1, nb ^ 1);
        const u16* a_ = lA + nb * 4096;
        const u16* b_ = lB + nb * 4096;
        bf16x8 af[4], bfr[4];
#pragma unroll
        for (int i = 0; i < 4; i++) {
            af[i]  = *(const bf16x8*)(a_ + (wr * 64 + i * 16 + lr) * 32 + lg * 8);
            bfr[i] = *(const bf16x8*)(b_ + (wc * 64 + i * 16 + lr) * 32 + lg * 8);
        }
        __builtin_amdgcn_s_setprio(1);
#pragma unroll
        for (int mi = 0; mi < 4; mi++)
#pragma unroll
            for (int ni = 0; ni < 4; ni++)
                acc[mi][ni] = __builtin_amdgcn_mfma_f32_16x16x32_bf16(
                    af[mi], bfr[ni], acc[mi][ni], 0, 0, 0);
        __builtin_amdgcn_s_setprio(0);
        asm volatile("s_waitcnt vmcnt(0)" ::: "memory");
        __syncthreads();
        nb ^= 1;
    }

    if (MODE == 0) {
        int seg = n0 >> 10;                       // block-uniform
        float ss = (seg == 0) ? QSCALE : 1.0f;
        u16* outb = (seg == 0) ? Qg : (seg == 1) ? Kg : VTg;
#pragma unroll
        for (int mi = 0; mi < 4; mi++)
#pragma unroll
            for (int ni = 0; ni < 4; ni++) {
                int ng = n0 + wc * 64 + ni * 16 + lr;
                int ngl = ng & 1023;
                int h = ngl >> 6, d = ngl & 63;
                int mg0 = m0 + wr * 64 + mi * 16 + lg * 4;
                int bb = mg0 >> 11, tq0 = mg0 & 2047;
                float bsv = bias[ng];
                if (seg == 2) {
                    ushort4 o;
                    o.x = f2bf(acc[mi][ni][0] + bsv);
                    o.y = f2bf(acc[mi][ni][1] + bsv);
                    o.z = f2bf(acc[mi][ni][2] + bsv);
                    o.w = f2bf(acc[mi][ni][3] + bsv);
                    *(ushort4*)&VTg[(((size_t)(bb * NHEAD + h)) * HDIM + d) * TSEQ + tq0] = o;
                } else {
#pragma unroll
                    for (int r = 0; r < 4; r++) {
                        float v = acc[mi][ni][r] * ss + bsv;
                        outb[(((size_t)(bb * NHEAD + h)) * TSEQ + tq0 + r) * HDIM + d] = f2bf(v);
                    }
                }
            }
    } else {
#pragma unroll
        for (int mi = 0; mi < 4; mi++)
#pragma unroll
            for (int ni = 0; ni < 4; ni++) {
                int ng = n0 + wc * 64 + ni * 16 + lr;
                int mg0 = m0 + wr * 64 + mi * 16 + lg * 4;
                float bsv = bias[ng];
#pragma unroll
                for (int r = 0; r < 4; r++)
                    Fout[(size_t)(mg0 + r) * DMODEL + ng] = acc[mi][ni][r] + bsv;
            }
    }
}

// ---------------- flash attention: 32x32 swapped, in-register softmax ----------------
// Q: [bh][T][64] bf16 pre-scaled by QSCALE; K: [bh][T][64]; VT: [bh][64][T]; O: [M][D] bf16
// block = 4 waves, 32 q/wave = 128 q-rows per pass; 2 passes (q-super p and 15-p)
__global__ __launch_bounds__(256) void attn(const u16* __restrict__ Qg,
                                            const u16* __restrict__ Kg,
                                            const u16* __restrict__ VTg,
                                            u16* __restrict__ Og) {
    __shared__ __align__(16) u16 sK[2 * 4096];
    __shared__ __align__(16) u16 sV[2 * 4096];
    const int bh = blockIdx.x;       // 0..63  (stride-64 ids -> same XCD per bh)
    const int p  = blockIdx.y;       // 0..7
    const int tid = threadIdx.x;
    const int wv = tid >> 6;
    const int l  = tid & 63;
    const int ln = l & 31;
    const int hi = l >> 5;
    const int b = bh >> 4, h = bh & 15;

    auto STAGE = [&](int tt, int nbuf) {
        int kv0s = tt << 6;
#pragma unroll
        for (int s = 0; s < 2; ++s) {
            int cc = tid + s * 256;
            int row = cc >> 3, c = cc & 7;
            int csrc = c ^ (row & 7);
            GLOAD16(Kg + ((size_t)bh * TSEQ + kv0s + row) * HDIM + csrc * 8,
                    sK + nbuf * 4096 + (s * 256 + wv * 64) * 8);
            GLOAD16(VTg + ((size_t)bh * HDIM + row) * TSEQ + kv0s + csrc * 8,
                    sV + nbuf * 4096 + (s * 256 + wv * 64) * 8);
        }
    };

    for (int pass = 0; pass < 2; ++pass) {
        const int sidx = pass ? (15 - p) : p;
        const int qs = sidx << 7;
        const int NT = (qs >> 6) + 2;
        const int q0w = qs + wv * 32;
        const int qglob = q0w + ln;

        bf16x8 qf0, qf1, qf2, qf3;
        {
            const u16* qb = Qg + ((size_t)bh * TSEQ + qglob) * HDIM + hi * 8;
            qf0 = *(const bf16x8*)(qb);
            qf1 = *(const bf16x8*)(qb + 16);
            qf2 = *(const bf16x8*)(qb + 32);
            qf3 = *(const bf16x8*)(qb + 48);
        }
        float mrun = -INFINITY, lsum = 0.f;
        f32x16 accO0, accO1;
#pragma unroll
        for (int i = 0; i < 16; ++i) { accO0[i] = 0.f; accO1[i] = 0.f; }

        int nb = 0;
        STAGE(0, 0);
        asm volatile("s_waitcnt vmcnt(0)" ::: "memory");
        __syncthreads();

        for (int t = 0; t < NT; ++t) {
            if (t + 1 < NT) STAGE(t + 1, nb ^ 1);
            const int kv0 = t << 6;
            if (kv0 <= q0w + 31) {          // wave-uniform active check
                const u16* sKb = sK + nb * 4096;
                const u16* sVb = sV + nb * 4096;
                f32x16 sc0, sc1;
#pragma unroll
                for (int i = 0; i < 16; ++i) { sc0[i] = 0.f; sc1[i] = 0.f; }
                __builtin_amdgcn_s_setprio(1);
#pragma unroll
                for (int c = 0; c < 4; ++c) {
                    int u = ((c << 1) | hi) ^ (ln & 7);
                    bf16x8 kf0 = *(const bf16x8*)(sKb + ln * 64 + u * 8);
                    bf16x8 kf1 = *(const bf16x8*)(sKb + (32 + ln) * 64 + u * 8);
                    bf16x8 qq = (c == 0) ? qf0 : (c == 1) ? qf1 : (c == 2) ? qf2 : qf3;
                    sc0 = __builtin_amdgcn_mfma_f32_32x32x16_bf16(kf0, qq, sc0, 0, 0, 0);
                    sc1 = __builtin_amdgcn_mfma_f32_32x32x16_bf16(kf1, qq, sc1, 0, 0, 0);
                }
                __builtin_amdgcn_s_setprio(0);

                if (kv0 + 63 > q0w) {       // diagonal tile: apply causal mask
                    const int qrel = qglob - kv0;
#pragma unroll
                    for (int r = 0; r < 16; ++r) {
                        int e0 = (r & 3) + 8 * (r >> 2) + 4 * hi;
                        if (e0 > qrel) sc0[r] = -INFINITY;
                        if (e0 + 32 > qrel) sc1[r] = -INFINITY;
                    }
                }

                float pmax = -INFINITY;
#pragma unroll
                for (int r = 0; r < 16; ++r) pmax = fmaxf(pmax, fmaxf(sc0[r], sc1[r]));
                pmax = fmaxf(pmax, __shfl_xor(pmax, 32, 64));
                const float nm = fmaxf(mrun, pmax);
                const float fc = exp2f(mrun - nm);
                mrun = nm;
                float ps = 0.f;
#pragma unroll
                for (int r = 0; r < 16; ++r) {
                    sc0[r] = exp2f(sc0[r] - nm);
                    sc1[r] = exp2f(sc1[r] - nm);
                    ps += sc0[r] + sc1[r];
                }
                ps += __shfl_xor(ps, 32, 64);
                lsum = lsum * fc + ps;
#pragma unroll
                for (int i = 0; i < 16; ++i) { accO0[i] *= fc; accO1[i] *= fc; }

                // pack P -> bf16 B-fragments via cvt_pk + permlane32_swap (no LDS)
                bf16x8 pf[4];
#pragma unroll
                for (int c = 0; c < 4; ++c) {
                    const int bb = (c & 1) * 8;
                    float s0, s1, s2, s3, s4, s5, s6, s7;
                    if (c < 2) {
                        s0 = sc0[bb + 0]; s1 = sc0[bb + 1]; s2 = sc0[bb + 2]; s3 = sc0[bb + 3];
                        s4 = sc0[bb + 4]; s5 = sc0[bb + 5]; s6 = sc0[bb + 6]; s7 = sc0[bb + 7];
                    } else {
                        s0 = sc1[bb + 0]; s1 = sc1[bb + 1]; s2 = sc1[bb + 2]; s3 = sc1[bb + 3];
                        s4 = sc1[bb + 4]; s5 = sc1[bb + 5]; s6 = sc1[bb + 6]; s7 = sc1[bb + 7];
                    }
                    u32 A  = cvtpk(s0, s1);
                    u32 A2 = cvtpk(s2, s3);
                    u32 Bp = cvtpk(s4, s5);
                    u32 B2 = cvtpk(s6, s7);
                    u32x2 r02 = __builtin_amdgcn_permlane32_swap(A, Bp, 0, 0);
                    u32x2 r13 = __builtin_amdgcn_permlane32_swap(A2, B2, 0, 0);
                    union { u32 w[4]; bf16x8 v; } pu;
                    pu.w[0] = r02[0]; pu.w[1] = r13[0];
                    pu.w[2] = r02[1]; pu.w[3] = r13[1];
                    pf[c] = pu.v;
                }

                __builtin_amdgcn_s_setprio(1);
#pragma unroll
                for (int c = 0; c < 4; ++c) {
                    int u = ((c << 1) | hi) ^ (ln & 7);
                    bf16x8 vf0 = *(const bf16x8*)(sVb + ln * 64 + u * 8);
                    bf16x8 vf1 = *(const bf16x8*)(sVb + (32 + ln) * 64 + u * 8);
                    accO0 = __builtin_amdgcn_mfma_f32_32x32x16_bf16(vf0, pf[c], accO0, 0, 0, 0);
                    accO1 = __builtin_amdgcn_mfma_f32_32x32x16_bf16(vf1, pf[c], accO1, 0, 0, 0);
                }
                __builtin_amdgcn_s_setprio(0);
            }
            asm volatile("s_waitcnt vmcnt(0)" ::: "memory");
            __syncthreads();
            nb ^= 1;
        }

        const float linv = 1.0f / lsum;
        u16* orow = Og + ((size_t)(b * TSEQ + qglob)) * DMODEL + h * HDIM;
#pragma unroll
        for (int a = 0; a < 4; ++a) {
            int d0 = 8 * a + 4 * hi;
            uint2 wo;
            wo.x = cvtpk(accO0[4 * a + 0] * linv, accO0[4 * a + 1] * linv);
            wo.y = cvtpk(accO0[4 * a + 2] * linv, accO0[4 * a + 3] * linv);
            *(uint2*)(orow + d0) = wo;
            wo.x = cvtpk(accO1[4 * a + 0] * linv, accO1[4 * a + 1] * linv);
            wo.y = cvtpk(accO1[4 * a + 2] * linv, accO1[4 * a + 3] * linv);
            *(uint2*)(orow + 32 + d0) = wo;
        }
    }
}

// ---------------- launch ----------------
extern "C" void kernel_launch(void* const* d_in, const int* in_sizes, int n_in,
                              void* d_out, int out_size, void* d_ws, size_t ws_size,
                              hipStream_t stream) {
    const float* x  = (const float*)d_in[0];
    const float* Wq = (const float*)d_in[1];
    const float* bq = (const float*)d_in[2];
    const float* Wk = (const float*)d_in[3];
    const float* bk = (const float*)d_in[4];
    const float* Wv = (const float*)d_in[5];
    const float* bv = (const float*)d_in[6];
    const float* Wo = (const float*)d_in[7];
    const float* bo = (const float*)d_in[8];
    float* out = (float*)d_out;

    u16* ws  = (u16*)d_ws;
    u16* xb  = ws;
    u16* WqT = xb  + (size_t)MTOT * DMODEL;
    u16* WkT = WqT + (size_t)DMODEL * DMODEL;
    u16* WvT = WkT + (size_t)DMODEL * DMODEL;
    u16* WoT = WvT + (size_t)DMODEL * DMODEL;
    u16* Qg  = WoT + (size_t)DMODEL * DMODEL;
    u16* Kg  = Qg  + (size_t)MTOT * DMODEL;
    u16* VTg = Kg  + (size_t)MTOT * DMODEL;
    u16* Og  = VTg + (size_t)MTOT * DMODEL;
    float* biasP = (float*)(Og + (size_t)MTOT * DMODEL);   // 3072 floats

    cvt_x<<<(MTOT * DMODEL) / (256 * 4), 256, 0, stream>>>(x, xb);
    dim3 tg(16, 16);
    wtrans<<<tg, 256, 0, stream>>>(Wq, WqT);
    wtrans<<<tg, 256, 0, stream>>>(Wk, WkT);
    wtrans<<<tg, 256, 0, stream>>>(Wv, WvT);
    wtrans<<<tg, 256, 0, stream>>>(Wo, WoT);
    pack_bias<<<12, 256, 0, stream>>>(bq, bk, bv, biasP);

    // fused QKV: N = 3072 (WqT|WkT|WvT contiguous)
    gemm_bt<0><<<dim3(24, MTOT / 128), 256, 0, stream>>>(xb, WqT, biasP,
                                                         Qg, Kg, VTg, nullptr, DMODEL);

    attn<<<dim3(64, 8), 256, 0, stream>>>(Qg, Kg, VTg, Og);

    gemm_bt<3><<<dim3(8, MTOT / 128), 256, 0, stream>>>(Og, WoT, bo,
                                                        nullptr, nullptr, nullptr, out, DMODEL);
}